// Round 9
// baseline (2189.073 us; speedup 1.0000x reference)
//
#include <hip/hip_runtime.h>

// 2-layer stacked LSTM (shared cell), B=256, T=1024, F=UNITS=128 — MFMA v6.
// 32 LSTM WGs (512 thr, 8 waves) x 8 batch; blocks 32..255 fill zeros output.
//
// Repacked chains (one shared h-tile + x-only chain):
//   tile(k) = [h1(k-1) b0-7 ; h2(k-2) b0-7]   (16 rows, read ONCE)
//   chainU = tile@U : rows0-7 = h1@U (z1 part), rows8-15 = h2@U (z2 part)
//   chainW = tile@W : rows0-7 = h1@W (z2 part, shfl_xor(32) to z2 lanes)
//   chainX (even k<=1022) = [x(k+1); x(k+2)]@W -> zx(k+1) rows0-7,
//     zx(k+2) rows8-15, carried in accX regs across ticks. Odd ticks consume
//     rows0-7 direct; even ticks shfl_xor(32) rows8-15 before overwrite.
//   z1 = bias + chainU(rows0-7) + zx ; z2 = bias + chainU(rows8-15) + shfl(chainW).
// chainX is h-independent -> placed LAST with the tail transcendentals
// spliced between its MFMAs (matrix pipe busy while trans pipe drains).
// x prefetch: global load x(k+3) each tick -> LDS x-pair ring (dist 3).
// One barrier per tick.
//
// d_out (f32): [0,32768) h2_final | [32768,+33554432) zeros | [33587200,..) c1

typedef _Float16 f16;
typedef _Float16 f16x2 __attribute__((ext_vector_type(2)));
typedef _Float16 f16x8 __attribute__((ext_vector_type(8)));
typedef float    f32x4 __attribute__((ext_vector_type(4)));

#define T_STEPS 1024
#define UNITS   128
#define NLSTM   32
#define BPW     8
#define NBLK    256
#define OUT_ZERO 32768
#define OUT_C1   33587200

#define MFMA16(A, B, C) __builtin_amdgcn_mfma_f32_16x16x32_f16((A), (B), (C), 0, 0, 0)

__device__ __forceinline__ float frcp_(float x) {
#if __has_builtin(__builtin_amdgcn_rcpf)
    return __builtin_amdgcn_rcpf(x);
#else
    return 1.0f / x;
#endif
}
__device__ __forceinline__ float sigmoidf_(float x) {
    return frcp_(1.0f + __expf(-x));
}
__device__ __forceinline__ float tanhf_(float x) {
    float e = __expf(2.0f * x);
    return 1.0f - 2.0f * frcp_(e + 1.0f);
}
__device__ __forceinline__ unsigned pkh(float a, float b) {
    f16x2 t; t[0] = (f16)a; t[1] = (f16)b;
    return __builtin_bit_cast(unsigned, t);
}
// swizzled byte address in a 16-row x 256B tile
__device__ __forceinline__ int swb(int row, int byteoff) {
    return row * 256 + (byteoff ^ ((row & 7) << 4));
}

__global__ __launch_bounds__(512, 2) void lstm2_kernel(
    const float* __restrict__ X,   // [256][1024][128]
    const float* __restrict__ W,   // [128][512] gate order i|f|g|o
    const float* __restrict__ U,   // [128][512]
    const float* __restrict__ Bv,  // [512]
    float* __restrict__ out)
{
    const int blk = blockIdx.x;
    const int tid = threadIdx.x;

    if (blk >= NLSTM) {
        // ---------- zeros-output fill on idle CUs ----------
        const size_t nthr = (size_t)(NBLK - NLSTM) * 512;
        float4* dst = (float4*)(out + OUT_ZERO);
        const float4 z4 = make_float4(0.f, 0.f, 0.f, 0.f);
        for (size_t i = (size_t)(blk - NLSTM) * 512 + tid; i < 8388608u; i += nthr)
            dst[i] = z4;
        return;
    }

    // ---------- LSTM workgroup ----------
    const int w  = tid >> 6;        // wave = unit block [16w,16w+16)
    const int l  = tid & 63;
    const int lr = l & 15;          // A row / C col (unit within block)
    const int lc = l >> 4;          // k-chunk / C row group
    const int u  = w * 16 + lr;     // unit in [0,128)
    const int b0 = blk * BPW;
    const bool cell2 = (lc >= 2);
    const size_t xstride = (size_t)(T_STEPS * UNITS);

    __shared__ __align__(16) char hb[2][4096];   // [h1; h2] tiles, dbuf
    __shared__ __align__(16) char xb[2][4096];   // [x(odd); x(even)] pair ring

    // ---- weight B-fragments (resident): [gate][ktile], 8 f16 each
    f16x8 Wf[4][4], Uf[4][4];
    #pragma unroll
    for (int g = 0; g < 4; ++g) {
        #pragma unroll
        for (int kt = 0; kt < 4; ++kt) {
            f16x8 wt, ut;
            #pragma unroll
            for (int j = 0; j < 8; ++j) {
                const int krow = kt * 32 + lc * 8 + j;
                wt[j] = (f16)W[(size_t)krow * 512 + g * 128 + u];
                ut[j] = (f16)U[(size_t)krow * 512 + g * 128 + u];
            }
            Wf[g][kt] = wt;  Uf[g][kt] = ut;
        }
    }
    float bias[4];
    #pragma unroll
    for (int g = 0; g < 4; ++g) bias[g] = Bv[g * 128 + u];

    // ---- frag read addresses (row lr, 16B per kt)
    int ard[4];
    #pragma unroll
    for (int kt = 0; kt < 4; ++kt) ard[kt] = swb(lr, kt * 64 + lc * 16);
    int hwaddr[4];
    #pragma unroll
    for (int e = 0; e < 4; ++e) hwaddr[e] = swb(4 * lc + e, u * 2);

    // ---- init: zero h tiles; prologue x writes (x0->xb1 r0-7, x1->xb0 r0-7, x2->xb0 r8-15)
    for (int i = tid; i < 2048; i += 512) ((float*)hb)[i] = 0.0f;
    {
        const int r = tid >> 6, c = (tid & 63) * 2;
        const float* Xb = X + (size_t)(b0 + r) * xstride + c;
        const float2 v0 = *(const float2*)(Xb);
        const float2 v1 = *(const float2*)(Xb + UNITS);
        const float2 v2 = *(const float2*)(Xb + 2 * UNITS);
        *(unsigned*)(&xb[1][0] + swb(r, c * 2))     = pkh(v0.x, v0.y);
        *(unsigned*)(&xb[0][0] + swb(r, c * 2))     = pkh(v1.x, v1.y);
        *(unsigned*)(&xb[0][0] + swb(8 + r, c * 2)) = pkh(v2.x, v2.y);
    }
    __syncthreads();

    // ---- chainX_pre: zx(0) = [x0;x0]@W (rows 0-7 used)
    f32x4 accX[4];
    {
        f16x8 Ax[4];
        #pragma unroll
        for (int kt = 0; kt < 4; ++kt)
            Ax[kt] = *(const f16x8*)(&xb[1][0] + swb(lr & 7, kt * 64 + lc * 16));
        #pragma unroll
        for (int g = 0; g < 4; ++g) accX[g] = f32x4{0.f, 0.f, 0.f, 0.f};
        #pragma unroll
        for (int kt = 0; kt < 4; ++kt)
            #pragma unroll
            for (int g = 0; g < 4; ++g)
                accX[g] = MFMA16(Ax[kt], Wf[g][kt], accX[g]);
    }
    __syncthreads();   // protect xb[1] before tick0's x3 write

    float cst[4] = {0.f, 0.f, 0.f, 0.f};   // c1 (lc<2) / c2 (lc>=2)

    for (int k = 0; k <= T_STEPS; ++k) {
        const int hrd = (k & 1) * 4096, hwr = 4096 - hrd;
        const bool even = !(k & 1);
        const bool runX = even && (k <= 1022);
        const int xrd = ((k >> 1) & 1) * 4096;

        // ---- zx for this tick (from accX of a previous tick)
        const bool dir = (!even) || (k == 0);
        float zxv[4][4];
        #pragma unroll
        for (int g = 0; g < 4; ++g)
            #pragma unroll
            for (int e = 0; e < 4; ++e) {
                const float v = accX[g][e];
                const float s = __shfl_xor(v, 32);
                zxv[g][e] = dir ? v : s;
            }

        // ---- global x(k+3) prefetch (consumed by LDS write at tick end)
        const int m = k + 3;
        const bool ldx = (m <= 1023);
        const int xr = tid >> 6, xc = (tid & 63) * 2;
        float2 xv = make_float2(0.f, 0.f);
        if (ldx) xv = *(const float2*)(X + (size_t)(b0 + xr) * xstride + (size_t)m * UNITS + xc);

        // ---- A-frag reads: h tile first, then x pair
        f16x8 Ah[4];
        #pragma unroll
        for (int kt = 0; kt < 4; ++kt)
            Ah[kt] = *(const f16x8*)(&hb[0][0] + hrd + ard[kt]);
        f16x8 Ax[4];
        if (runX) {
            #pragma unroll
            for (int kt = 0; kt < 4; ++kt)
                Ax[kt] = *(const f16x8*)(&xb[0][0] + xrd + ard[kt]);
        }

        // ---- chainW: h-tile @ W (rows0-7 = h1@W for z2)
        f32x4 accW[4];
        #pragma unroll
        for (int g = 0; g < 4; ++g) accW[g] = f32x4{0.f, 0.f, 0.f, 0.f};
        #pragma unroll
        for (int kt = 0; kt < 4; ++kt)
            #pragma unroll
            for (int g = 0; g < 4; ++g)
                accW[g] = MFMA16(Ah[kt], Wf[g][kt], accW[g]);

        // ---- chainU g,o with z2v shfl spliced (VALU under MFMA)
        f32x4 aug = {bias[2], bias[2], bias[2], bias[2]};
        f32x4 auo = {bias[3], bias[3], bias[3], bias[3]};
        float z2v[4][4];
        aug = MFMA16(Ah[0], Uf[2][0], aug);  auo = MFMA16(Ah[0], Uf[3][0], auo);
        z2v[0][0] = __shfl_xor(accW[0][0], 32);  z2v[0][1] = __shfl_xor(accW[0][1], 32);
        z2v[0][2] = __shfl_xor(accW[0][2], 32);  z2v[0][3] = __shfl_xor(accW[0][3], 32);
        aug = MFMA16(Ah[1], Uf[2][1], aug);  auo = MFMA16(Ah[1], Uf[3][1], auo);
        z2v[1][0] = __shfl_xor(accW[1][0], 32);  z2v[1][1] = __shfl_xor(accW[1][1], 32);
        z2v[1][2] = __shfl_xor(accW[1][2], 32);  z2v[1][3] = __shfl_xor(accW[1][3], 32);
        aug = MFMA16(Ah[2], Uf[2][2], aug);  auo = MFMA16(Ah[2], Uf[3][2], auo);
        z2v[2][0] = __shfl_xor(accW[2][0], 32);  z2v[2][1] = __shfl_xor(accW[2][1], 32);
        z2v[2][2] = __shfl_xor(accW[2][2], 32);  z2v[2][3] = __shfl_xor(accW[2][3], 32);
        aug = MFMA16(Ah[3], Uf[2][3], aug);  auo = MFMA16(Ah[3], Uf[3][3], auo);
        z2v[3][0] = __shfl_xor(accW[3][0], 32);  z2v[3][1] = __shfl_xor(accW[3][1], 32);
        z2v[3][2] = __shfl_xor(accW[3][2], 32);  z2v[3][3] = __shfl_xor(accW[3][3], 32);

        // ---- chainU i,f with g/o combine+trans spliced
        f32x4 aui = {bias[0], bias[0], bias[0], bias[0]};
        f32x4 auf = {bias[1], bias[1], bias[1], bias[1]};
        float gg[4], oo[4];
        aui = MFMA16(Ah[0], Uf[0][0], aui);  auf = MFMA16(Ah[0], Uf[1][0], auf);
        { const float zg = aug[0] + (cell2 ? z2v[2][0] : zxv[2][0]); gg[0] = tanhf_(zg);
          const float zo = auo[0] + (cell2 ? z2v[3][0] : zxv[3][0]); oo[0] = sigmoidf_(zo); }
        aui = MFMA16(Ah[1], Uf[0][1], aui);  auf = MFMA16(Ah[1], Uf[1][1], auf);
        { const float zg = aug[1] + (cell2 ? z2v[2][1] : zxv[2][1]); gg[1] = tanhf_(zg);
          const float zo = auo[1] + (cell2 ? z2v[3][1] : zxv[3][1]); oo[1] = sigmoidf_(zo); }
        aui = MFMA16(Ah[2], Uf[0][2], aui);  auf = MFMA16(Ah[2], Uf[1][2], auf);
        { const float zg = aug[2] + (cell2 ? z2v[2][2] : zxv[2][2]); gg[2] = tanhf_(zg);
          const float zo = auo[2] + (cell2 ? z2v[3][2] : zxv[3][2]); oo[2] = sigmoidf_(zo); }
        aui = MFMA16(Ah[3], Uf[0][3], aui);  auf = MFMA16(Ah[3], Uf[1][3], auf);
        { const float zg = aug[3] + (cell2 ? z2v[2][3] : zxv[2][3]); gg[3] = tanhf_(zg);
          const float zo = auo[3] + (cell2 ? z2v[3][3] : zxv[3][3]); oo[3] = sigmoidf_(zo); }

        // ---- tail-1: sigma(i,f) + c update
        const bool active = cell2 ? (k > 0) : (k < T_STEPS);
        float cn[4];
        #pragma unroll
        for (int e = 0; e < 4; ++e) {
            const float zi = aui[e] + (cell2 ? z2v[0][e] : zxv[0][e]);
            const float zf = auf[e] + (cell2 ? z2v[1][e] : zxv[1][e]);
            const float ig = sigmoidf_(zi), fg = sigmoidf_(zf);
            cn[e] = fg * cst[e] + ig * gg[e];
            if (active) cst[e] = cn[e];
        }

        // ---- chainX (even ticks) with tail-2 spliced; else plain tail-2
        float hq[4];
        if (runX) {
            #pragma unroll
            for (int g = 0; g < 4; ++g) accX[g] = f32x4{0.f, 0.f, 0.f, 0.f};
            accX[0] = MFMA16(Ax[0], Wf[0][0], accX[0]);
            accX[1] = MFMA16(Ax[0], Wf[1][0], accX[1]);
            accX[2] = MFMA16(Ax[0], Wf[2][0], accX[2]);
            accX[3] = MFMA16(Ax[0], Wf[3][0], accX[3]);
            hq[0] = oo[0] * tanhf_(cn[0]);
            accX[0] = MFMA16(Ax[1], Wf[0][1], accX[0]);
            accX[1] = MFMA16(Ax[1], Wf[1][1], accX[1]);
            accX[2] = MFMA16(Ax[1], Wf[2][1], accX[2]);
            accX[3] = MFMA16(Ax[1], Wf[3][1], accX[3]);
            hq[1] = oo[1] * tanhf_(cn[1]);
            accX[0] = MFMA16(Ax[2], Wf[0][2], accX[0]);
            accX[1] = MFMA16(Ax[2], Wf[1][2], accX[1]);
            accX[2] = MFMA16(Ax[2], Wf[2][2], accX[2]);
            accX[3] = MFMA16(Ax[2], Wf[3][2], accX[3]);
            hq[2] = oo[2] * tanhf_(cn[2]);
            accX[0] = MFMA16(Ax[3], Wf[0][3], accX[0]);
            accX[1] = MFMA16(Ax[3], Wf[1][3], accX[1]);
            accX[2] = MFMA16(Ax[3], Wf[2][3], accX[2]);
            accX[3] = MFMA16(Ax[3], Wf[3][3], accX[3]);
            hq[3] = oo[3] * tanhf_(cn[3]);
        } else {
            #pragma unroll
            for (int e = 0; e < 4; ++e) hq[e] = oo[e] * tanhf_(cn[e]);
        }

        // ---- LDS writes: h (single placement) + x(k+3)
        if (active && k < T_STEPS) {
            #pragma unroll
            for (int e = 0; e < 4; ++e)
                *(f16*)(&hb[0][0] + hwr + hwaddr[e]) = (f16)hq[e];
        }
        if (ldx) {
            const int row  = (m & 1) ? xr : (8 + xr);
            const int slot = (m & 1) ? (((m - 1) >> 1) & 1) : (((m - 2) >> 1) & 1);
            *(unsigned*)(&xb[0][0] + slot * 4096 + swb(row, xc * 2)) = pkh(xv.x, xv.y);
        }

        // ---- final outputs
        if (k == T_STEPS - 1 && !cell2) {
            #pragma unroll
            for (int e = 0; e < 4; ++e)
                out[OUT_C1 + (size_t)(b0 + 4 * lc + e) * UNITS + u] = cst[e];
        }
        if (k == T_STEPS && cell2) {
            #pragma unroll
            for (int e = 0; e < 4; ++e)
                out[(size_t)(b0 + 4 * (lc - 2) + e) * UNITS + u] = hq[e];
        }
        __syncthreads();
    }
}

extern "C" void kernel_launch(void* const* d_in, const int* in_sizes, int n_in,
                              void* d_out, int out_size, void* d_ws, size_t ws_size,
                              hipStream_t stream) {
    const float* X  = (const float*)d_in[0];
    const float* W  = (const float*)d_in[1];
    const float* U  = (const float*)d_in[2];
    const float* Bv = (const float*)d_in[3];
    float* out = (float*)d_out;
    hipLaunchKernelGGL(lstm2_kernel, dim3(NBLK), dim3(512), 0, stream,
                       X, W, U, Bv, out);
}

// Round 10
// 1245.671 us; speedup vs baseline: 1.7573x; 1.7573x over previous
//
#include <hip/hip_runtime.h>

// 2-layer stacked LSTM (shared cell), B=256, T=1024, F=UNITS=128 — MFMA v7.
// = v5 (round 7, 1102us) with staggered gate completion:
//   P1: g,o chains (16 MFMA, ILP2)
//   P2: i chain (8 MFMA) with tanh(g)/sigma(o) spliced (dep-free: g,o done)
//   P3: f chain (8 MFMA) with sigma(i) + x-LDS-write spliced
//   tail: sigma(f) + c update + tanh(c) + h write   (16 trans ops vs v5's 24)
//
// 32 LSTM WGs (512 thr, 8 waves) x 8 batch rows (full M=16 = 8 batch x 2
// cells); blocks 32..255 fill the zeros output.
// Per tick k: acc = A1@W + A2@U, A1 = rows 0-15 [x(k); h1(k-1)],
// A2 = rows 8-23 [h1(k-1); h2(k-2)]. acc rows 0-7 = z1 (cell1 step k),
// rows 8-15 = z2 (cell2 step k-1). Epilogue acc-lane-local; lanes lc<2 run
// cell1, lc>=2 run cell2. One barrier per tick.
//
// d_out (f32): [0,32768) h2_final | [32768,+33554432) zeros | [33587200,..) c1

typedef _Float16 f16;
typedef _Float16 f16x2 __attribute__((ext_vector_type(2)));
typedef _Float16 f16x8 __attribute__((ext_vector_type(8)));
typedef float    f32x4 __attribute__((ext_vector_type(4)));

#define T_STEPS 1024
#define UNITS   128
#define NLSTM   32
#define BPW     8
#define NBLK    256
#define OUT_ZERO 32768
#define OUT_C1   33587200
#define BUFB    6144   // 24 rows * 256B (x:0-7, h1:8-15, h2:16-23)

#define MFMA16(A, B, C) __builtin_amdgcn_mfma_f32_16x16x32_f16((A), (B), (C), 0, 0, 0)

__device__ __forceinline__ float frcp_(float x) {
#if __has_builtin(__builtin_amdgcn_rcpf)
    return __builtin_amdgcn_rcpf(x);
#else
    return 1.0f / x;
#endif
}
__device__ __forceinline__ float sigmoidf_(float x) {
    return frcp_(1.0f + __expf(-x));
}
__device__ __forceinline__ float tanhf_(float x) {
    float e = __expf(2.0f * x);
    return 1.0f - 2.0f * frcp_(e + 1.0f);
}
__device__ __forceinline__ unsigned pkh(float a, float b) {
    f16x2 t; t[0] = (f16)a; t[1] = (f16)b;
    return __builtin_bit_cast(unsigned, t);
}

__global__ __launch_bounds__(512, 2) void lstm2_kernel(
    const float* __restrict__ X,   // [256][1024][128]
    const float* __restrict__ W,   // [128][512] gate order i|f|g|o
    const float* __restrict__ U,   // [128][512]
    const float* __restrict__ Bv,  // [512]
    float* __restrict__ out)
{
    const int blk = blockIdx.x;
    const int tid = threadIdx.x;

    if (blk >= NLSTM) {
        // ---------- zeros-output fill on idle CUs ----------
        const size_t nthr = (size_t)(NBLK - NLSTM) * 512;
        float4* dst = (float4*)(out + OUT_ZERO);
        const float4 z4 = make_float4(0.f, 0.f, 0.f, 0.f);
        for (size_t i = (size_t)(blk - NLSTM) * 512 + tid; i < 8388608u; i += nthr)
            dst[i] = z4;
        return;
    }

    // ---------- LSTM workgroup ----------
    const int w  = tid >> 6;        // wave = unit block [16w,16w+16)
    const int l  = tid & 63;
    const int lr = l & 15;          // A row / C col (unit within block)
    const int lc = l >> 4;          // k-chunk / C row group
    const int u  = w * 16 + lr;     // unit in [0,128)
    const int b0 = blk * BPW;
    const bool cell2 = (l >= 32);

    __shared__ __align__(16) char Abuf[2][BUFB];
    char* Ab = (char*)Abuf;

    // ---- weight B-fragments (resident): [gate][ktile], 8 f16 each
    f16x8 Wf[4][4], Uf[4][4];
    #pragma unroll
    for (int g = 0; g < 4; ++g) {
        #pragma unroll
        for (int kt = 0; kt < 4; ++kt) {
            f16x8 wt, ut;
            #pragma unroll
            for (int j = 0; j < 8; ++j) {
                const int krow = kt * 32 + lc * 8 + j;
                wt[j] = (f16)W[(size_t)krow * 512 + g * 128 + u];
                ut[j] = (f16)U[(size_t)krow * 512 + g * 128 + u];
            }
            Wf[g][kt] = wt;  Uf[g][kt] = ut;
        }
    }
    float bias[4];
    #pragma unroll
    for (int g = 0; g < 4; ++g) bias[g] = Bv[g * 128 + u];

    // ---- precomputed swizzled addresses (lane constants)
    const int swz = (lr & 7) << 4;
    int raddr[2][4];
    #pragma unroll
    for (int a0 = 0; a0 < 2; ++a0)
        #pragma unroll
        for (int kt = 0; kt < 4; ++kt)
            raddr[a0][kt] = (((a0 * 8 + lr) * 256) + kt * 64 + lc * 16) ^ swz;
    int waddr[4];
    #pragma unroll
    for (int e = 0; e < 4; ++e)
        waddr[e] = ((8 + 4 * lc + e) * 256 + u * 2) ^ ((((4 * lc + e) & 7)) << 4);

    // ---- init LDS: zero both buffers, load x[0] into buf0 rows 0-7
    for (int i = tid; i < 3072; i += 512) ((float*)Ab)[i] = 0.0f;
    {
        const int flat = tid * 2, xr = flat >> 7, xc = flat & 127;
        const float2 xv = *(const float2*)(X + (size_t)(b0 + xr) * (T_STEPS * UNITS) + xc);
        const int byte = ((xr * 256 + xc * 2) ^ ((xr & 7) << 4));
        *(unsigned*)(Ab + byte) = pkh(xv.x, xv.y);
    }
    __syncthreads();

    float cst[4] = {0.f, 0.f, 0.f, 0.f};   // c1 (lanes<32) / c2 (lanes>=32)

    for (int k = 0; k <= T_STEPS; ++k) {
        const int rdo = (k & 1) * BUFB, wro = BUFB - rdo;

        // issue x[k+1] prefetch early (hides HBM latency under MFMA phase)
        float xa = 0.f, xb = 0.f; int xr = 0, xc = 0;
        if (k + 1 < T_STEPS) {
            const int flat = tid * 2; xr = flat >> 7; xc = flat & 127;
            const float2 xv = *(const float2*)(X + (size_t)(b0 + xr) * (T_STEPS * UNITS)
                                                 + (size_t)(k + 1) * UNITS + xc);
            xa = xv.x; xb = xv.y;
        }

        // ---- A fragments from LDS
        f16x8 A1[4], A2[4];
        #pragma unroll
        for (int kt = 0; kt < 4; ++kt) {
            A1[kt] = *(const f16x8*)(Ab + rdo + raddr[0][kt]);
            A2[kt] = *(const f16x8*)(Ab + rdo + raddr[1][kt]);
        }

        // ---- P1: g,o chains (16 MFMA, ILP2)
        f32x4 accg = {bias[2], bias[2], bias[2], bias[2]};
        f32x4 acco = {bias[3], bias[3], bias[3], bias[3]};
        #pragma unroll
        for (int kt = 0; kt < 4; ++kt) {
            accg = MFMA16(A1[kt], Wf[2][kt], accg);
            acco = MFMA16(A1[kt], Wf[3][kt], acco);
        }
        #pragma unroll
        for (int kt = 0; kt < 4; ++kt) {
            accg = MFMA16(A2[kt], Uf[2][kt], accg);
            acco = MFMA16(A2[kt], Uf[3][kt], acco);
        }

        // ---- P2: i chain (8 MFMA) with tanh(g)/sigma(o) spliced (dep-free)
        f32x4 acci = {bias[0], bias[0], bias[0], bias[0]};
        float gg[4], oo[4];
        acci = MFMA16(A1[0], Wf[0][0], acci);
        gg[0] = tanhf_(accg[0]);
        acci = MFMA16(A1[1], Wf[0][1], acci);
        oo[0] = sigmoidf_(acco[0]);
        acci = MFMA16(A1[2], Wf[0][2], acci);
        gg[1] = tanhf_(accg[1]);
        acci = MFMA16(A1[3], Wf[0][3], acci);
        oo[1] = sigmoidf_(acco[1]);
        acci = MFMA16(A2[0], Uf[0][0], acci);
        gg[2] = tanhf_(accg[2]);
        acci = MFMA16(A2[1], Uf[0][1], acci);
        oo[2] = sigmoidf_(acco[2]);
        acci = MFMA16(A2[2], Uf[0][2], acci);
        gg[3] = tanhf_(accg[3]);
        acci = MFMA16(A2[3], Uf[0][3], acci);
        oo[3] = sigmoidf_(acco[3]);

        // ---- P3: f chain (8 MFMA) with sigma(i) + x-LDS-write spliced
        f32x4 accf = {bias[1], bias[1], bias[1], bias[1]};
        float si[4];
        accf = MFMA16(A1[0], Wf[1][0], accf);
        si[0] = sigmoidf_(acci[0]);
        accf = MFMA16(A1[1], Wf[1][1], accf);
        si[1] = sigmoidf_(acci[1]);
        accf = MFMA16(A1[2], Wf[1][2], accf);
        si[2] = sigmoidf_(acci[2]);
        accf = MFMA16(A1[3], Wf[1][3], accf);
        si[3] = sigmoidf_(acci[3]);
        accf = MFMA16(A2[0], Uf[1][0], accf);
        if (k + 1 < T_STEPS) {      // x(k+1) -> write buffer rows 0-7
            const int byte = ((xr * 256 + xc * 2) ^ ((xr & 7) << 4));
            *(unsigned*)(Ab + wro + byte) = pkh(xa, xb);
        }
        accf = MFMA16(A2[1], Uf[1][1], accf);
        accf = MFMA16(A2[2], Uf[1][2], accf);
        accf = MFMA16(A2[3], Uf[1][3], accf);

        // ---- tail: sigma(f) + c update + tanh(c) + h writes (per-e ASAP)
        const bool active = cell2 ? (k > 0) : (k < T_STEPS);
        const bool wact = active && (k < T_STEPS);
        float hq[4];
        #pragma unroll
        for (int e = 0; e < 4; ++e) {
            const float fg = sigmoidf_(accf[e]);
            const float cn = fg * cst[e] + si[e] * gg[e];
            if (active) cst[e] = cn;
            hq[e] = oo[e] * tanhf_(cn);
            if (wact)
                *(f16*)(Ab + wro + waddr[e]) = (f16)hq[e];
        }

        // ---- final outputs
        if (k == T_STEPS - 1 && !cell2) {
            #pragma unroll
            for (int e = 0; e < 4; ++e)
                out[OUT_C1 + (size_t)(b0 + 4 * lc + e) * UNITS + u] = cst[e];
        }
        if (k == T_STEPS && cell2) {
            #pragma unroll
            for (int e = 0; e < 4; ++e)
                out[(size_t)(b0 + 4 * lc + e - 8) * UNITS + u] = hq[e];
        }
        __syncthreads();
    }
}

extern "C" void kernel_launch(void* const* d_in, const int* in_sizes, int n_in,
                              void* d_out, int out_size, void* d_ws, size_t ws_size,
                              hipStream_t stream) {
    const float* X  = (const float*)d_in[0];
    const float* W  = (const float*)d_in[1];
    const float* U  = (const float*)d_in[2];
    const float* Bv = (const float*)d_in[3];
    float* out = (float*)d_out;
    hipLaunchKernelGGL(lstm2_kernel, dim3(NBLK), dim3(512), 0, stream,
                       X, W, U, Bv, out);
}